// Round 1
// baseline (640.521 us; speedup 1.0000x reference)
//
#include <hip/hip_runtime.h>
#include <hip/hip_bf16.h>

// Workspace layout (floats)
#define OFF_COLSUM 0        // 64
#define OFF_S      64       // 4096
#define OFF_SCXY   4160     // 64
#define OFF_SHXY   4224     // 64
#define OFF_SCZ    4288     // 64
#define OFF_SHZ    4352     // 64
#define OFF_W1XYT  4416     // 4096 (w1_xy transposed: [j][k])
#define OFF_W1ZT   8512     // 4096
#define OFF_WSEGT  12608    // 1280 (w_seg transposed: [s][k])
#define OFF_ACC    13888    // 8 loss accumulators
#define WS_FLOATS  13896

#define TS 32  // rows per LDS tile in stats pass

// ---------------- Pass 1: colsum + S = feat^T feat ----------------
__global__ __launch_bounds__(256) void k_stats(const float* __restrict__ feat,
                                               int N, float* __restrict__ ws) {
    __shared__ float tile[TS][64];
    float acc[4][4];
#pragma unroll
    for (int a = 0; a < 4; a++)
#pragma unroll
        for (int b = 0; b < 4; b++) acc[a][b] = 0.f;
    float csum = 0.f;

    const int t  = threadIdx.x;
    const int tx = t & 15;       // j-block
    const int ty = t >> 4;       // i-block
    const int ntiles = (N + TS - 1) / TS;

    for (int ti = blockIdx.x; ti < ntiles; ti += gridDim.x) {
        const int row0 = ti * TS;
        const float4* src = (const float4*)(feat + (size_t)row0 * 64);
        float4* dst = (float4*)(&tile[0][0]);
#pragma unroll
        for (int u = 0; u < 2; u++) {
            int idx = t + u * 256;          // float4 index in tile (512 total)
            int r   = idx >> 4;
            float4 v = make_float4(0.f, 0.f, 0.f, 0.f);
            if (row0 + r < N) v = src[idx];
            dst[idx] = v;
        }
        __syncthreads();

#pragma unroll 8
        for (int r = 0; r < TS; r++) {
            float4 fi4 = *(const float4*)&tile[r][ty * 4];
            float4 fj4 = *(const float4*)&tile[r][tx * 4];
            float fi[4] = {fi4.x, fi4.y, fi4.z, fi4.w};
            float fj[4] = {fj4.x, fj4.y, fj4.z, fj4.w};
#pragma unroll
            for (int a = 0; a < 4; a++)
#pragma unroll
                for (int b = 0; b < 4; b++) acc[a][b] = fmaf(fi[a], fj[b], acc[a][b]);
        }
        if (t < 64) {
#pragma unroll 8
            for (int r = 0; r < TS; r++) csum += tile[r][t];
        }
        __syncthreads();
    }

    float* S = ws + OFF_S;
#pragma unroll
    for (int a = 0; a < 4; a++)
#pragma unroll
        for (int b = 0; b < 4; b++)
            atomicAdd(&S[(ty * 4 + a) * 64 + (tx * 4 + b)], acc[a][b]);
    if (t < 64) atomicAdd(&ws[OFF_COLSUM + t], csum);
}

// ------------- Prep: BN scale/shift from (colsum,S); transposes -------------
__global__ __launch_bounds__(256) void k_prep(
    const float* __restrict__ w1xy, const float* __restrict__ b1xy,
    const float* __restrict__ gxy,  const float* __restrict__ bexy,
    const float* __restrict__ w1z,  const float* __restrict__ b1z,
    const float* __restrict__ gz,   const float* __restrict__ bez,
    const float* __restrict__ wseg, float Nf, float* __restrict__ ws) {
    __shared__ float S[64][64];
    __shared__ float cs[64];
    const int t = threadIdx.x;

    for (int i = t; i < 4096; i += 256) ((float*)S)[i] = ws[OFF_S + i];
    if (t < 64) cs[t] = ws[OFF_COLSUM + t];

    // transposes (independent of S)
    for (int i = t; i < 4096; i += 256) {
        int k = i >> 6, j = i & 63;
        ws[OFF_W1XYT + j * 64 + k] = w1xy[i];
        ws[OFF_W1ZT  + j * 64 + k] = w1z[i];
    }
    for (int i = t; i < 1280; i += 256) {
        int k = i / 20, s = i % 20;
        ws[OFF_WSEGT + s * 64 + k] = wseg[i];
    }
    __syncthreads();

    if (t < 128) {
        const int head = t >> 6, j = t & 63;
        const float* w1 = head ? w1z : w1xy;
        float w[64];
#pragma unroll
        for (int k = 0; k < 64; k++) w[k] = w1[k * 64 + j];
        float d = 0.f;
#pragma unroll
        for (int k = 0; k < 64; k++) d = fmaf(cs[k], w[k], d);
        float quad = 0.f;
#pragma unroll
        for (int k = 0; k < 64; k++) {
            float rd = 0.f;
#pragma unroll
            for (int l = 0; l < 64; l++) rd = fmaf(S[k][l], w[l], rd);
            quad = fmaf(w[k], rd, quad);
        }
        const float b1 = head ? b1z[j] : b1xy[j];
        const float mu  = d / Nf + b1;
        const float eh2 = quad / Nf + 2.f * b1 * d / Nf + b1 * b1;
        const float var = eh2 - mu * mu;
        const float g  = head ? gz[j]  : gxy[j];
        const float be = head ? bez[j] : bexy[j];
        const float sc = g * rsqrtf(var + 1e-3f);
        const float sh = be - mu * sc;
        ws[(head ? OFF_SCZ : OFF_SCXY) + j] = sc;
        ws[(head ? OFF_SHZ : OFF_SHXY) + j] = sh;
    }
}

// ---------------- Pass 2: per-row heads + losses ----------------
__global__ __launch_bounds__(256) void k_loss(
    const float* __restrict__ feat, const float* __restrict__ coord,
    const int* __restrict__ seg, const int* __restrict__ inst,
    const float* __restrict__ cent,
    const float* __restrict__ w1xyT, const float* __restrict__ w1zT,
    const float* __restrict__ wsegT,
    const float* __restrict__ scxy, const float* __restrict__ shxy,
    const float* __restrict__ scz,  const float* __restrict__ shz,
    const float* __restrict__ w2xy, const float* __restrict__ b2xy,
    const float* __restrict__ w2z,  const float* __restrict__ b2z,
    const float* __restrict__ bseg,
    int N, float* __restrict__ acc) {
    const int row = blockIdx.x * 256 + threadIdx.x;
    float s_nll = 0.f, s_vf = 0.f, s_l1xy = 0.f, s_cosxy = 0.f;
    float s_l1z = 0.f, s_cosz = 0.f, s_mask = 0.f;

    if (row < N) {
        float f[64];
        const float4* fp = (const float4*)(feat + (size_t)row * 64);
#pragma unroll
        for (int u = 0; u < 16; u++) {
            float4 v = fp[u];
            f[u * 4 + 0] = v.x; f[u * 4 + 1] = v.y;
            f[u * 4 + 2] = v.z; f[u * 4 + 3] = v.w;
        }

        float pxy0 = b2xy[0], pxy1 = b2xy[1], pz = b2z[0];
#pragma unroll 2
        for (int j = 0; j < 64; j++) {
            const float* wx = w1xyT + j * 64;
            const float* wz = w1zT + j * 64;
            float ax = 0.f, az = 0.f;
#pragma unroll
            for (int k = 0; k < 64; k++) {
                ax = fmaf(f[k], wx[k], ax);
                az = fmaf(f[k], wz[k], az);
            }
            float hx = fmaxf(fmaf(ax, scxy[j], shxy[j]), 0.f);
            float hz = fmaxf(fmaf(az, scz[j],  shz[j]),  0.f);
            pxy0 = fmaf(hx, w2xy[j * 2 + 0], pxy0);
            pxy1 = fmaf(hx, w2xy[j * 2 + 1], pxy1);
            pz   = fmaf(hz, w2z[j], pz);
        }

        float lg[20];
#pragma unroll
        for (int s = 0; s < 20; s++) {
            const float* w = wsegT + s * 64;
            float a = bseg[s];
#pragma unroll
            for (int k = 0; k < 64; k++) a = fmaf(f[k], w[k], a);
            lg[s] = a;
        }
        float m = lg[0];
#pragma unroll
        for (int s = 1; s < 20; s++) m = fmaxf(m, lg[s]);
        float se = 0.f;
#pragma unroll
        for (int s = 0; s < 20; s++) se += __expf(lg[s] - m);
        const float lse = m + __logf(se);

        const int tg = seg[row];
        const bool valid = (tg != -1);
        const int tuse = valid ? tg : 0;
        float lt = lg[0];
#pragma unroll
        for (int s = 1; s < 20; s++) lt = (s == tuse) ? lg[s] : lt;
        const float vf = valid ? 1.f : 0.f;
        s_nll = (lse - lt) * vf;
        s_vf  = vf;

        const float mk = (inst[row] != -1) ? 1.f : 0.f;
        const float c0 = coord[row * 3 + 0], c1 = coord[row * 3 + 1], c2 = coord[row * 3 + 2];
        const float e0 = cent[row * 3 + 0],  e1 = cent[row * 3 + 1],  e2 = cent[row * 3 + 2];
        const float a0 = e0 - c0, a1 = e1 - c1, a2 = e2 - c2;

        s_l1xy = (fabsf(a0 - pxy0) + fabsf(a1 - pxy1)) * mk;
        const float na = sqrtf(a0 * a0 + a1 * a1) + 1e-8f;
        const float nb = sqrtf(pxy0 * pxy0 + pxy1 * pxy1) + 1e-8f;
        s_cosxy = -((a0 / na) * (pxy0 / nb) + (a1 / na) * (pxy1 / nb)) * mk;

        s_l1z = fabsf(a2 - pz) * mk;
        const float naz = fabsf(a2) + 1e-8f, nbz = fabsf(pz) + 1e-8f;
        s_cosz = -((a2 / naz) * (pz / nbz)) * mk;
        s_mask = mk;
    }

    // block reduction of 7 values
    float v[7] = {s_nll, s_vf, s_l1xy, s_cosxy, s_l1z, s_cosz, s_mask};
#pragma unroll
    for (int i = 0; i < 7; i++) {
#pragma unroll
        for (int o = 32; o > 0; o >>= 1) v[i] += __shfl_down(v[i], o);
    }
    __shared__ float red[4][8];
    const int lane = threadIdx.x & 63, wid = threadIdx.x >> 6;
    if (lane == 0) {
#pragma unroll
        for (int i = 0; i < 7; i++) red[wid][i] = v[i];
    }
    __syncthreads();
    if (threadIdx.x < 7) {
        float s = red[0][threadIdx.x] + red[1][threadIdx.x] +
                  red[2][threadIdx.x] + red[3][threadIdx.x];
        atomicAdd(&acc[threadIdx.x], s);
    }
}

// ---------------- Finalize ----------------
__global__ void k_fin(const float* __restrict__ acc, float* __restrict__ out) {
    const float sn = acc[0], sv = acc[1], sl1 = acc[2], scx = acc[3];
    const float slz = acc[4], scz = acc[5], sm = acc[6];
    const float segl = sn / sv;
    const float den = sm + 1e-8f;
    const float l1xy = sl1 / den, cosxy = scx / den;
    const float l1z = slz / den, cosz = scz / den;
    out[0] = segl + l1xy + l1xy + 0.5f * (l1z + cosz);
    out[1] = segl;
    out[2] = l1xy;
    out[3] = cosxy;
    out[4] = l1z;
    out[5] = cosz;
}

extern "C" void kernel_launch(void* const* d_in, const int* in_sizes, int n_in,
                              void* d_out, int out_size, void* d_ws, size_t ws_size,
                              hipStream_t stream) {
    const float* feat  = (const float*)d_in[0];
    const float* coord = (const float*)d_in[1];
    const int*   segm  = (const int*)d_in[2];
    const int*   inst  = (const int*)d_in[3];
    const float* cent  = (const float*)d_in[4];
    const float* w1xy  = (const float*)d_in[5];
    const float* b1xy  = (const float*)d_in[6];
    const float* gxy   = (const float*)d_in[7];
    const float* bexy  = (const float*)d_in[8];
    const float* w2xy  = (const float*)d_in[9];
    const float* b2xy  = (const float*)d_in[10];
    const float* w1z   = (const float*)d_in[11];
    const float* b1z   = (const float*)d_in[12];
    const float* gz    = (const float*)d_in[13];
    const float* bez   = (const float*)d_in[14];
    const float* w2z   = (const float*)d_in[15];
    const float* b2z   = (const float*)d_in[16];
    const float* wseg  = (const float*)d_in[17];
    const float* bseg  = (const float*)d_in[18];

    const int N = in_sizes[0] / 64;
    float* ws = (float*)d_ws;

    // zero colsum+S and the loss accumulators (harness poisons ws once, never re-poisons)
    hipMemsetAsync(d_ws, 0, (OFF_S + 4096) * sizeof(float), stream);
    hipMemsetAsync((char*)d_ws + OFF_ACC * sizeof(float), 0, 8 * sizeof(float), stream);

    k_stats<<<1024, 256, 0, stream>>>(feat, N, ws);
    k_prep<<<1, 256, 0, stream>>>(w1xy, b1xy, gxy, bexy, w1z, b1z, gz, bez, wseg,
                                  (float)N, ws);
    k_loss<<<(N + 255) / 256, 256, 0, stream>>>(
        feat, coord, segm, inst, cent,
        ws + OFF_W1XYT, ws + OFF_W1ZT, ws + OFF_WSEGT,
        ws + OFF_SCXY, ws + OFF_SHXY, ws + OFF_SCZ, ws + OFF_SHZ,
        w2xy, b2xy, w2z, b2z, bseg, N, ws + OFF_ACC);
    k_fin<<<1, 1, 0, stream>>>(ws + OFF_ACC, (float*)d_out);
}

// Round 2
// 308.757 us; speedup vs baseline: 2.0745x; 2.0745x over previous
//
#include <hip/hip_runtime.h>
#include <hip/hip_bf16.h>

// Workspace layout (floats)
#define OFF_COLSUM 0        // 64
#define OFF_S      64       // 4096
#define OFF_SCXY   4160     // 64
#define OFF_SHXY   4224     // 64
#define OFF_SCZ    4288     // 64
#define OFF_SHZ    4352     // 64
#define OFF_W1XYT  4416     // 4096 (w1_xy transposed: [j][k])
#define OFF_W1ZT   8512     // 4096
#define OFF_WSEGT  12608    // 1280 (w_seg transposed: [s][k])
#define OFF_ACC    13888    // 8 loss accumulators

typedef __attribute__((ext_vector_type(8))) short bf16x8;
typedef __attribute__((ext_vector_type(4))) float f32x4;

__device__ __forceinline__ unsigned short f2bf(float f) {
    unsigned int u = __float_as_uint(f);
    return (unsigned short)((u + 0x7fffu + ((u >> 16) & 1u)) >> 16);
}
// XOR swizzle for row-major [R][64] bf16 tiles: kills the stride-128B bank conflict
__device__ __forceinline__ int swz(int r, int k) { return r * 64 + (k ^ ((r & 7) << 3)); }

// ---------------- Pass 1: colsum + S = feat^T feat (8x8 reg blocking) ----------------
__global__ __launch_bounds__(256) void k_stats(const float* __restrict__ feat,
                                               int N, float* __restrict__ ws) {
    __shared__ float tile[64 * 64];  // 16 KB, linear row-major fp32
    float acc[8][8];
#pragma unroll
    for (int a = 0; a < 8; a++)
#pragma unroll
        for (int b = 0; b < 8; b++) acc[a][b] = 0.f;
    float csum = 0.f;

    const int t  = threadIdx.x;
    const int wv = t >> 6;
    const int i0 = ((t >> 3) & 7) * 8;
    const int j0 = (t & 7) * 8;
    const int ntiles = (N + 63) >> 6;

    for (int ti = blockIdx.x; ti < ntiles; ti += gridDim.x) {
        __syncthreads();
        const int row0 = ti * 64;
        const float4* src = (const float4*)(feat + (size_t)row0 * 64);
#pragma unroll
        for (int u = 0; u < 4; u++) {
            int idx = t + u * 256;  // float4 units, 1024 total
            float4 v = make_float4(0.f, 0.f, 0.f, 0.f);
            if (row0 + (idx >> 4) < N) v = src[idx];
            *(float4*)&tile[idx * 4] = v;
        }
        __syncthreads();

#pragma unroll 4
        for (int rr = 0; rr < 16; rr++) {
            const float* row = &tile[(wv * 16 + rr) * 64];
            float4 a0 = *(const float4*)&row[i0];
            float4 a1 = *(const float4*)&row[i0 + 4];
            float4 b0 = *(const float4*)&row[j0];
            float4 b1 = *(const float4*)&row[j0 + 4];
            float fa[8] = {a0.x, a0.y, a0.z, a0.w, a1.x, a1.y, a1.z, a1.w};
            float fb[8] = {b0.x, b0.y, b0.z, b0.w, b1.x, b1.y, b1.z, b1.w};
#pragma unroll
            for (int a = 0; a < 8; a++)
#pragma unroll
                for (int b = 0; b < 8; b++) acc[a][b] = fmaf(fa[a], fb[b], acc[a][b]);
            csum += row[t & 63];
        }
    }

    // cross-wave combine of S in LDS, then one atomicAdd per element per block
    __syncthreads();
    for (int w = 0; w < 4; w++) {
        if (wv == w) {
#pragma unroll
            for (int a = 0; a < 8; a++)
#pragma unroll
                for (int b = 0; b < 8; b++) {
                    float* p = &tile[(i0 + a) * 64 + (j0 + b)];
                    if (w == 0) *p = acc[a][b]; else *p += acc[a][b];
                }
        }
        __syncthreads();
    }
    float* S = ws + OFF_S;
    for (int i = t; i < 4096; i += 256) atomicAdd(&S[i], tile[i]);
    __syncthreads();
    tile[t] = csum;
    __syncthreads();
    if (t < 64) {
        float s = tile[t] + tile[t + 64] + tile[t + 128] + tile[t + 192];
        atomicAdd(&ws[OFF_COLSUM + t], s);
    }
}

// ------------- Prep: BN scale/shift from (colsum,S); transposes -------------
__global__ __launch_bounds__(256) void k_prep(
    const float* __restrict__ w1xy, const float* __restrict__ b1xy,
    const float* __restrict__ gxy,  const float* __restrict__ bexy,
    const float* __restrict__ w1z,  const float* __restrict__ b1z,
    const float* __restrict__ gz,   const float* __restrict__ bez,
    const float* __restrict__ wseg, float Nf, float* __restrict__ ws) {
    __shared__ float S[64][64];
    __shared__ float cs[64];
    const int t = threadIdx.x;

    for (int i = t; i < 4096; i += 256) ((float*)S)[i] = ws[OFF_S + i];
    if (t < 64) cs[t] = ws[OFF_COLSUM + t];

    for (int i = t; i < 4096; i += 256) {
        int k = i >> 6, j = i & 63;
        ws[OFF_W1XYT + j * 64 + k] = w1xy[i];
        ws[OFF_W1ZT  + j * 64 + k] = w1z[i];
    }
    for (int i = t; i < 1280; i += 256) {
        int k = i / 20, s = i % 20;
        ws[OFF_WSEGT + s * 64 + k] = wseg[i];
    }
    __syncthreads();

    if (t < 128) {
        const int head = t >> 6, j = t & 63;
        const float* w1 = head ? w1z : w1xy;
        float w[64];
#pragma unroll
        for (int k = 0; k < 64; k++) w[k] = w1[k * 64 + j];
        float d = 0.f;
#pragma unroll
        for (int k = 0; k < 64; k++) d = fmaf(cs[k], w[k], d);
        float quad = 0.f;
#pragma unroll
        for (int k = 0; k < 64; k++) {
            float rd = 0.f;
#pragma unroll
            for (int l = 0; l < 64; l++) rd = fmaf(S[k][l], w[l], rd);
            quad = fmaf(w[k], rd, quad);
        }
        const float b1 = head ? b1z[j] : b1xy[j];
        const float mu  = d / Nf + b1;
        const float eh2 = quad / Nf + 2.f * b1 * d / Nf + b1 * b1;
        const float var = eh2 - mu * mu;
        const float g  = head ? gz[j]  : gxy[j];
        const float be = head ? bez[j] : bexy[j];
        const float sc = g * rsqrtf(var + 1e-3f);
        const float sh = be - mu * sc;
        ws[(head ? OFF_SCZ : OFF_SCXY) + j] = sc;
        ws[(head ? OFF_SHZ : OFF_SHXY) + j] = sh;
    }
}

// ---------------- Pass 2: MFMA heads + losses ----------------
__global__ __launch_bounds__(256) void k_loss(
    const float* __restrict__ feat, const float* __restrict__ coord,
    const int* __restrict__ seg, const int* __restrict__ inst,
    const float* __restrict__ cent,
    const float* __restrict__ w1xyT, const float* __restrict__ w1zT,
    const float* __restrict__ wsegT,
    const float* __restrict__ scxy, const float* __restrict__ shxy,
    const float* __restrict__ scz,  const float* __restrict__ shz,
    const float* __restrict__ w2xy, const float* __restrict__ b2xy,
    const float* __restrict__ w2z,  const float* __restrict__ b2z,
    const float* __restrict__ bseg,
    int N, float* __restrict__ acc) {
    __shared__ __align__(16) unsigned short ft[64 * 64];   // feat tile bf16, swizzled
    __shared__ __align__(16) unsigned short wxs[64 * 64];  // w1_xy^T bf16, swizzled
    __shared__ __align__(16) unsigned short wzs[64 * 64];  // w1_z^T bf16, swizzled
    __shared__ __align__(16) unsigned short wgs[32 * 64];  // w_seg^T bf16 (rows 20..31 = 0)
    __shared__ float ccA[192], ccB[192];                   // coord / centroid for tile
    __shared__ int sgl[64], itl[64];

    const int t    = threadIdx.x;
    const int lane = t & 63;
    const int l15  = lane & 15;
    const int grp  = lane >> 4;
    const int wv   = t >> 6;

    // stage weights -> bf16 swizzled LDS (once per block)
#pragma unroll
    for (int u = 0; u < 4; u++) {
        int idx = t + u * 256;           // float4 unit over 64x64
        int j = idx >> 4, k0 = (idx & 15) * 4;
        float4 vx = *(const float4*)&w1xyT[idx * 4];
        float4 vz = *(const float4*)&w1zT[idx * 4];
        ushort4 hx = {f2bf(vx.x), f2bf(vx.y), f2bf(vx.z), f2bf(vx.w)};
        ushort4 hz = {f2bf(vz.x), f2bf(vz.y), f2bf(vz.z), f2bf(vz.w)};
        *(ushort4*)&wxs[swz(j, k0)] = hx;
        *(ushort4*)&wzs[swz(j, k0)] = hz;
    }
    {
        int idx = t + 256;  // cover 512 float4 units (32x64) with 2 rounds
        int j0i = t >> 4, k00 = (t & 15) * 4;
        float4 v = (j0i < 20) ? *(const float4*)&wsegT[t * 4] : make_float4(0, 0, 0, 0);
        ushort4 h = {f2bf(v.x), f2bf(v.y), f2bf(v.z), f2bf(v.w)};
        *(ushort4*)&wgs[swz(j0i, k00)] = h;
        int j1 = idx >> 4, k01 = (idx & 15) * 4;
        float4 v2 = (j1 < 20) ? *(const float4*)&wsegT[idx * 4] : make_float4(0, 0, 0, 0);
        ushort4 h2 = {f2bf(v2.x), f2bf(v2.y), f2bf(v2.z), f2bf(v2.w)};
        *(ushort4*)&wgs[swz(j1, k01)] = h2;
    }

    // per-lane constants (col = nt*16 + l15)
    float scx4[4], shx4[4], scz4[4], shz4[4], w2x0[4], w2x1[4], w2zz[4];
#pragma unroll
    for (int nt = 0; nt < 4; nt++) {
        const int c = nt * 16 + l15;
        scx4[nt] = scxy[c]; shx4[nt] = shxy[c];
        scz4[nt] = scz[c];  shz4[nt] = shz[c];
        w2x0[nt] = w2xy[c * 2]; w2x1[nt] = w2xy[c * 2 + 1]; w2zz[nt] = w2z[c];
    }
    const float pb0 = b2xy[0], pb1 = b2xy[1], pbz = b2z[0];
    const float bs0 = bseg[l15];
    const float bs1 = (l15 < 4) ? bseg[16 + l15] : 0.f;

    float s_nll = 0.f, s_vf = 0.f, s_l1xy = 0.f, s_cosxy = 0.f;
    float s_l1z = 0.f, s_cosz = 0.f, s_mask = 0.f;

    const int ntiles = (N + 63) >> 6;
    const f32x4 z4 = {0.f, 0.f, 0.f, 0.f};

    for (int ti = blockIdx.x; ti < ntiles; ti += gridDim.x) {
        const int row0 = ti * 64;
        __syncthreads();  // previous iteration's LDS reads done

        // stage feat tile -> bf16 swizzled
        const float4* fsrc = (const float4*)(feat + (size_t)row0 * 64);
#pragma unroll
        for (int u = 0; u < 4; u++) {
            int idx = t + u * 256;
            int r = idx >> 4, k0 = (idx & 15) * 4;
            float4 v = make_float4(0.f, 0.f, 0.f, 0.f);
            if (row0 + r < N) v = fsrc[idx];
            ushort4 h = {f2bf(v.x), f2bf(v.y), f2bf(v.z), f2bf(v.w)};
            *(ushort4*)&ft[swz(r, k0)] = h;
        }
        // stage coord/cent/seg/inst
        if (row0 + 64 <= N) {
            if (t < 48) {
                *(float4*)&ccA[t * 4] = *(const float4*)&coord[(size_t)row0 * 3 + t * 4];
                *(float4*)&ccB[t * 4] = *(const float4*)&cent[(size_t)row0 * 3 + t * 4];
            }
            if (t >= 64 && t < 128) { sgl[t - 64] = seg[row0 + t - 64]; }
            if (t >= 128 && t < 192) { itl[t - 128] = inst[row0 + t - 128]; }
        } else if (t < 64) {
            int r = row0 + t;
            bool ok = r < N;
            ccA[t * 3] = ok ? coord[(size_t)r * 3] : 0.f;
            ccA[t * 3 + 1] = ok ? coord[(size_t)r * 3 + 1] : 0.f;
            ccA[t * 3 + 2] = ok ? coord[(size_t)r * 3 + 2] : 0.f;
            ccB[t * 3] = ok ? cent[(size_t)r * 3] : 0.f;
            ccB[t * 3 + 1] = ok ? cent[(size_t)r * 3 + 1] : 0.f;
            ccB[t * 3 + 2] = ok ? cent[(size_t)r * 3 + 2] : 0.f;
            sgl[t] = ok ? seg[r] : -1;
            itl[t] = ok ? inst[r] : -1;
        }
        __syncthreads();

        // ---- MFMA: this wave owns rows 16*wv .. 16*wv+15 ----
        const int arow = wv * 16 + l15;
        const int k0 = grp * 8;
        bf16x8 a0 = *(const bf16x8*)&ft[swz(arow, k0)];
        bf16x8 a1 = *(const bf16x8*)&ft[swz(arow, k0 + 32)];
        f32x4 cx[4], cz4a[4], cg[2];
#pragma unroll
        for (int nt = 0; nt < 4; nt++) {
            const int br = nt * 16 + l15;
            bf16x8 b0 = *(const bf16x8*)&wxs[swz(br, k0)];
            bf16x8 b1 = *(const bf16x8*)&wxs[swz(br, k0 + 32)];
            cx[nt] = __builtin_amdgcn_mfma_f32_16x16x32_bf16(a0, b0, z4, 0, 0, 0);
            cx[nt] = __builtin_amdgcn_mfma_f32_16x16x32_bf16(a1, b1, cx[nt], 0, 0, 0);
            b0 = *(const bf16x8*)&wzs[swz(br, k0)];
            b1 = *(const bf16x8*)&wzs[swz(br, k0 + 32)];
            cz4a[nt] = __builtin_amdgcn_mfma_f32_16x16x32_bf16(a0, b0, z4, 0, 0, 0);
            cz4a[nt] = __builtin_amdgcn_mfma_f32_16x16x32_bf16(a1, b1, cz4a[nt], 0, 0, 0);
        }
#pragma unroll
        for (int nt = 0; nt < 2; nt++) {
            const int br = nt * 16 + l15;
            bf16x8 b0 = *(const bf16x8*)&wgs[swz(br, k0)];
            bf16x8 b1 = *(const bf16x8*)&wgs[swz(br, k0 + 32)];
            cg[nt] = __builtin_amdgcn_mfma_f32_16x16x32_bf16(a0, b0, z4, 0, 0, 0);
            cg[nt] = __builtin_amdgcn_mfma_f32_16x16x32_bf16(a1, b1, cg[nt], 0, 0, 0);
        }

        // ---- tail: C row = (grp*4 + rg), col = nt*16 + l15; 16-lane group reductions ----
#pragma unroll
        for (int rg = 0; rg < 4; rg++) {
            const int row = wv * 16 + grp * 4 + rg;  // row within tile
            float s0 = 0.f, s1 = 0.f, szv = 0.f;
#pragma unroll
            for (int nt = 0; nt < 4; nt++) {
                float hx = fmaxf(fmaf(cx[nt][rg], scx4[nt], shx4[nt]), 0.f);
                float hz = fmaxf(fmaf(cz4a[nt][rg], scz4[nt], shz4[nt]), 0.f);
                s0 = fmaf(hx, w2x0[nt], s0);
                s1 = fmaf(hx, w2x1[nt], s1);
                szv = fmaf(hz, w2zz[nt], szv);
            }
#pragma unroll
            for (int d = 1; d < 16; d <<= 1) {
                s0 += __shfl_xor(s0, d);
                s1 += __shfl_xor(s1, d);
                szv += __shfl_xor(szv, d);
            }
            const float p0 = s0 + pb0, p1 = s1 + pb1, pzv = szv + pbz;

            // cross-entropy (classes spread over the 16-lane group)
            float lg0 = cg[0][rg] + bs0;
            const bool v1 = (l15 < 4);
            float lg1 = v1 ? (cg[1][rg] + bs1) : -1e30f;
            float mx = fmaxf(lg0, lg1);
#pragma unroll
            for (int d = 1; d < 16; d <<= 1) mx = fmaxf(mx, __shfl_xor(mx, d));
            float ex = __expf(lg0 - mx) + (v1 ? __expf(lg1 - mx) : 0.f);
#pragma unroll
            for (int d = 1; d < 16; d <<= 1) ex += __shfl_xor(ex, d);
            const float lse = mx + __logf(ex);
            const int tg = sgl[row];
            const float vf = (tg >= 0) ? 1.f : 0.f;
            const int tu = (tg >= 0) ? tg : 0;
            float lt = (l15 == tu) ? lg0 : 0.f;
            if (v1 && (16 + l15) == tu) lt += lg1;
#pragma unroll
            for (int d = 1; d < 16; d <<= 1) lt += __shfl_xor(lt, d);
            s_nll += (lse - lt) * vf;
            s_vf += vf;

            // bias losses (replicated x16, scaled later)
            const float mk = (itl[row] >= 0) ? 1.f : 0.f;
            const float c0v = ccA[row * 3], c1v = ccA[row * 3 + 1], c2v = ccA[row * 3 + 2];
            const float e0v = ccB[row * 3], e1v = ccB[row * 3 + 1], e2v = ccB[row * 3 + 2];
            const float a0v = e0v - c0v, a1v = e1v - c1v, a2v = e2v - c2v;
            s_l1xy += (fabsf(a0v - p0) + fabsf(a1v - p1)) * mk;
            const float na = sqrtf(a0v * a0v + a1v * a1v) + 1e-8f;
            const float nb = sqrtf(p0 * p0 + p1 * p1) + 1e-8f;
            s_cosxy -= ((a0v * p0 + a1v * p1) / (na * nb)) * mk;
            s_l1z += fabsf(a2v - pzv) * mk;
            const float naz = fabsf(a2v) + 1e-8f, nbz = fabsf(pzv) + 1e-8f;
            s_cosz -= ((a2v * pzv) / (naz * nbz)) * mk;
            s_mask += mk;
        }
    }

    // block reduction (values replicated x16 within each lane group -> scale 1/16)
    float v[7] = {s_nll * 0.0625f, s_vf * 0.0625f, s_l1xy * 0.0625f, s_cosxy * 0.0625f,
                  s_l1z * 0.0625f, s_cosz * 0.0625f, s_mask * 0.0625f};
#pragma unroll
    for (int i = 0; i < 7; i++) {
#pragma unroll
        for (int o = 32; o > 0; o >>= 1) v[i] += __shfl_down(v[i], o);
    }
    __shared__ float red[4][8];
    if (lane == 0) {
#pragma unroll
        for (int i = 0; i < 7; i++) red[wv][i] = v[i];
    }
    __syncthreads();
    if (t < 7) {
        float s = red[0][t] + red[1][t] + red[2][t] + red[3][t];
        atomicAdd(&acc[t], s);
    }
}

// ---------------- Finalize ----------------
__global__ void k_fin(const float* __restrict__ acc, float* __restrict__ out) {
    const float sn = acc[0], sv = acc[1], sl1 = acc[2], scx = acc[3];
    const float slz = acc[4], scz_ = acc[5], sm = acc[6];
    const float segl = sn / sv;
    const float den = sm + 1e-8f;
    const float l1xy = sl1 / den, cosxy = scx / den;
    const float l1z = slz / den, cosz = scz_ / den;
    out[0] = segl + l1xy + l1xy + 0.5f * (l1z + cosz);
    out[1] = segl;
    out[2] = l1xy;
    out[3] = cosxy;
    out[4] = l1z;
    out[5] = cosz;
}

extern "C" void kernel_launch(void* const* d_in, const int* in_sizes, int n_in,
                              void* d_out, int out_size, void* d_ws, size_t ws_size,
                              hipStream_t stream) {
    const float* feat  = (const float*)d_in[0];
    const float* coord = (const float*)d_in[1];
    const int*   segm  = (const int*)d_in[2];
    const int*   inst  = (const int*)d_in[3];
    const float* cent  = (const float*)d_in[4];
    const float* w1xy  = (const float*)d_in[5];
    const float* b1xy  = (const float*)d_in[6];
    const float* gxy   = (const float*)d_in[7];
    const float* bexy  = (const float*)d_in[8];
    const float* w2xy  = (const float*)d_in[9];
    const float* b2xy  = (const float*)d_in[10];
    const float* w1z   = (const float*)d_in[11];
    const float* b1z   = (const float*)d_in[12];
    const float* gz    = (const float*)d_in[13];
    const float* bez   = (const float*)d_in[14];
    const float* w2z   = (const float*)d_in[15];
    const float* b2z   = (const float*)d_in[16];
    const float* wseg  = (const float*)d_in[17];
    const float* bseg  = (const float*)d_in[18];

    const int N = in_sizes[0] / 64;
    float* ws = (float*)d_ws;

    hipMemsetAsync(d_ws, 0, (OFF_S + 4096) * sizeof(float), stream);
    hipMemsetAsync((char*)d_ws + OFF_ACC * sizeof(float), 0, 8 * sizeof(float), stream);

    k_stats<<<1024, 256, 0, stream>>>(feat, N, ws);
    k_prep<<<1, 256, 0, stream>>>(w1xy, b1xy, gxy, bexy, w1z, b1z, gz, bez, wseg,
                                  (float)N, ws);
    k_loss<<<2048, 256, 0, stream>>>(
        feat, coord, segm, inst, cent,
        ws + OFF_W1XYT, ws + OFF_W1ZT, ws + OFF_WSEGT,
        ws + OFF_SCXY, ws + OFF_SHXY, ws + OFF_SCZ, ws + OFF_SHZ,
        w2xy, b2xy, w2z, b2z, bseg, N, ws + OFF_ACC);
    k_fin<<<1, 1, 0, stream>>>(ws + OFF_ACC, (float*)d_out);
}